// Round 17
// baseline (196.015 us; speedup 1.0000x reference)
//
#include <hip/hip_runtime.h>
#include <math.h>

#define HH 512
#define WW 512
#define PP (HH * WW)          // 262144 pixels
#define GG 64                 // gt points per batch
#define BB 4                  // batches
#define THREADS 512
#define TILE 1024             // pixels per block (8 waves x 128-px segments)
#define NT (PP / TILE)        // 256 tiles per batch -> grid 256x4 = 1024 = exactly 4 blocks/CU
#define NBLK (NT * BB)
#define MAX_DIST 724.0773439350246f   // sqrt(512^2 + 512^2)
#define EPSV 1e-6f
#define BIGF 3.4e38f

// ws layout (floats):
//   ws[0]        : uint block-completion counter   (zeroed via memset)
//   ws[1..4]     : t1sum[b]  (atomicAdd, zeroed)
//   ws[5..8]     : nesum[b]  (atomicAdd, zeroed)
//   ws[16..271]  : gmin uint bits [BB][GG]         (0x7f7f7f7f via memset)

__device__ __forceinline__ float rdlane(float v, int l) {
    return __int_as_float(__builtin_amdgcn_readlane(__float_as_int(v), l));
}

__launch_bounds__(THREADS, 8)
__global__ void ghd_main(const float* __restrict__ prob_map,
                         const float* __restrict__ prob_y,
                         const float* __restrict__ gt,
                         const int*   __restrict__ osz,
                         float*       __restrict__ ws,
                         float*       __restrict__ out) {
    const int t    = blockIdx.x;   // tile
    const int b    = blockIdx.y;   // batch
    const int tid  = threadIdx.x;
    const int lane = tid & 63;
    const int wave = tid >> 6;     // 8 waves

    __shared__ float    wmin[8][GG];
    __shared__ float    s_t1[8], s_ne[8];
    __shared__ float    sres[4];
    __shared__ unsigned s_last;

    const float nf0 = (float)osz[2 * b]     * (1.0f / HH);
    const float nf1 = (float)osz[2 * b + 1] * (1.0f / WW);

    // lane l owns gt point l (for B) — per-lane registers
    const float2 gxy = ((const float2*)gt)[b * GG + lane];
    const float  gx  = nf0 * gxy.x;
    const float  gy  = nf1 * gxy.y;
    const float  py  = prob_y[b * GG + lane];

    // own 2 adjacent pixels; wave's 128-px segment lies within ONE image row
    const int    seg0 = t * TILE + wave * 128;
    const float2 p2   = ((const float2*)(prob_map + (size_t)b * PP + seg0))[lane];
    const int    pid0 = seg0 + 2 * lane;
    const float  nx0  = nf0 * (float)(pid0 >> 9);
    const float  nx1a = nf1 * (float)(pid0 & (WW - 1));

    // block-uniform bases for scalar (SGPR) loads in A
    const float* __restrict__ gtb = gt     + (size_t)b * GG * 2;
    const float* __restrict__ pyb = prob_y + (size_t)b * GG;

    // ===== A: term-1 for own 2 pixels; gt data via s_load (uniform addr) =====
    float ma = BIGF, mb = BIGF;
#pragma unroll
    for (int g = 0; g < GG; ++g) {
        float sgx = gtb[2 * g];          // uniform -> SGPR
        float sgy = gtb[2 * g + 1];      // uniform -> SGPR
        float spy = pyb[g];              // uniform -> SGPR
        float dx  = fmaf(-nf0, sgx, nx0);
        float dx2 = dx * dx;
        float da  = fmaf(-nf1, sgy, nx1a);
        float db  = da + nf1;
        float pq  = spy * spy;           // same-SGPR twice: one read port, legal
        ma = fminf(ma, pq * fmaf(da, da, dx2));   // min_g (py^2 * d^2)
        mb = fminf(mb, pq * fmaf(db, db, dx2));
    }
    float t1 = p2.x * __builtin_amdgcn_sqrtf(ma) + p2.y * __builtin_amdgcn_sqrtf(mb);
    float ne = p2.x + p2.y;

    // ===== B: term-2; lane owns g; p broadcast via readlane; incremental dy =====
    // dense = (1-p)M + p*py*d = M + p*(py*d - M);  dx^2 loop-invariant per segment
    const float dxw  = nf0 * (float)(seg0 >> 9) - gx;
    const float dx2w = dxw * dxw;
    const float negM = -MAX_DIST;       // hoisted (kept out of loop-literal position)
    const float posM =  MAX_DIST;
    float dya  = nf1 * (float)(seg0 & (WW - 1)) - gy;   // dy of pixel 0
    float dyb  = dya + nf1;                             // dy of pixel 1
    const float step = nf1 + nf1;
    float gm0 = BIGF, gm1 = BIGF;
#pragma unroll
    for (int k = 0; k < 64; ++k) {
        float qa  = rdlane(p2.x, k);              // p of pixel seg0+2k   (SGPR)
        float qb  = rdlane(p2.y, k);              // p of pixel seg0+2k+1 (SGPR)
        float ea  = __builtin_amdgcn_sqrtf(fmaf(dya, dya, dx2w));
        float eb  = __builtin_amdgcn_sqrtf(fmaf(dyb, dyb, dx2w));
        gm0 = fminf(gm0, fmaf(qa, fmaf(py, ea, negM), posM));
        gm1 = fminf(gm1, fmaf(qb, fmaf(py, eb, negM), posM));
        dya += step;
        dyb += step;
    }
    wmin[wave][lane] = fminf(gm0, gm1);

    // ===== block reductions =====
#pragma unroll
    for (int off = 1; off < 64; off <<= 1) {
        t1 += __shfl_xor(t1, off);
        ne += __shfl_xor(ne, off);
    }
    if (lane == 0) { s_t1[wave] = t1; s_ne[wave] = ne; }
    __syncthreads();

    if (tid == 0) {
        float st = 0.0f, sn = 0.0f;
#pragma unroll
        for (int w = 0; w < 8; ++w) { st += s_t1[w]; sn += s_ne[w]; }
        atomicAdd(&ws[1 + b], st);            // device-scope, coherent
        atomicAdd(&ws[5 + b], sn);
    }
    if (tid < GG) {
        float v = wmin[0][tid];
#pragma unroll
        for (int w = 1; w < 8; ++w) v = fminf(v, wmin[w][tid]);
        // device-scope atomicMin on uint bits: order-preserving for floats >= 0
        atomicMin(reinterpret_cast<unsigned*>(ws) + 16 + b * GG + tid, __float_as_uint(v));
    }

    // ===== fan-in: last block computes the output (atomics-only reads) =====
    __threadfence();
    if (tid == 0) {
        unsigned old = atomicAdd(reinterpret_cast<unsigned*>(ws), 1u);
        s_last = (old == NBLK - 1) ? 1u : 0u;
    }
    __syncthreads();
    if (s_last) {
        if (tid < BB * GG) {
            const int fb = tid >> 6, fg = tid & 63;
            unsigned* gm = reinterpret_cast<unsigned*>(ws) + 16;
            // coherent read-back: atomicMin with FLT_MAX bits returns current value
            float mv  = __uint_as_float(atomicMin(gm + fb * GG + fg, 0x7f7fffffu));
            float fpy = prob_y[fb * GG + fg];
            float pyf = (fpy > 0.2f) ? fpy : 0.0f;
#pragma unroll
            for (int off = 1; off < 64; off <<= 1) {
                mv  += __shfl_xor(mv, off);
                pyf += __shfl_xor(pyf, off);
            }
            if (fg == 0) {
                float t1s = atomicAdd(&ws[1 + fb], 0.0f);   // coherent read
                float nes = atomicAdd(&ws[5 + fb], 0.0f);
                sres[fb] = t1s / (nes + EPSV) + mv / (pyf + EPSV);
            }
        }
        __syncthreads();
        if (tid == 0) out[0] = 0.25f * (sres[0] + sres[1] + sres[2] + sres[3]);
    }
}

extern "C" void kernel_launch(void* const* d_in, const int* in_sizes, int n_in,
                              void* d_out, int out_size, void* d_ws, size_t ws_size,
                              hipStream_t stream) {
    const float* prob_map = (const float*)d_in[0];
    const float* prob_y   = (const float*)d_in[1];
    const float* gt       = (const float*)d_in[2];
    const int*   osz      = (const int*)d_in[3];
    float* out = (float*)d_out;
    float* ws  = (float*)d_ws;

    // counter + t1[4] + ne[4] -> zero; gmin bits -> 0x7f7f7f7f (3.39e38)
    hipMemsetAsync(ws, 0, 9 * sizeof(float), stream);
    hipMemsetAsync(ws + 16, 0x7f, BB * GG * sizeof(unsigned), stream);

    dim3 grid(NT, BB);   // 1024 blocks = exactly 4 blocks/CU on 256 CUs
    ghd_main<<<grid, THREADS, 0, stream>>>(prob_map, prob_y, gt, osz, ws, out);
}

// Round 18
// 83.885 us; speedup vs baseline: 2.3367x; 2.3367x over previous
//
#include <hip/hip_runtime.h>
#include <math.h>

#define HH 512
#define WW 512
#define PP (HH * WW)          // 262144 pixels
#define GG 64                 // gt points per batch
#define BB 4                  // batches
#define THREADS 512
#define TILE 1024             // pixels per block (8 waves x 128-px segments)
#define NT (PP / TILE)        // 256 tiles per batch -> grid 256x4 = 1024 = exactly 4 blocks/CU
#define MAX_DIST 724.0773439350246f   // sqrt(512^2 + 512^2)
#define EPSV 1e-6f
#define BIGF 3.4e38f

// ws layout:
//   gm  uint bits [BB][GG] : ws[0    .. 255]    (init 0x7f7f7f7f via memset)
//   t1p [BB][NT]           : ws[256  .. 1279]   (write-only partials, no init)
//   nep [BB][NT]           : ws[1280 .. 2303]

__device__ __forceinline__ float rdlane(float v, int l) {
    return __int_as_float(__builtin_amdgcn_readlane(__float_as_int(v), l));
}

__launch_bounds__(THREADS, 8)
__global__ void ghd_main(const float* __restrict__ prob_map,
                         const float* __restrict__ prob_y,
                         const float* __restrict__ gt,
                         const int*   __restrict__ osz,
                         float*       __restrict__ ws) {
    const int t    = blockIdx.x;   // tile
    const int b    = blockIdx.y;   // batch
    const int tid  = threadIdx.x;
    const int lane = tid & 63;
    const int wave = tid >> 6;     // 8 waves

    __shared__ float wmin[8][GG];
    __shared__ float s_t1[8], s_ne[8];

    const float nf0 = (float)osz[2 * b]     * (1.0f / HH);
    const float nf1 = (float)osz[2 * b + 1] * (1.0f / WW);

    // lane l owns gt point l (for B) — per-lane registers
    const float2 gxy = ((const float2*)gt)[b * GG + lane];
    const float  gx  = nf0 * gxy.x;
    const float  gy  = nf1 * gxy.y;
    const float  py  = prob_y[b * GG + lane];

    // own 2 adjacent pixels; wave's 128-px segment lies within ONE image row
    const int    seg0 = t * TILE + wave * 128;
    const float2 p2   = ((const float2*)(prob_map + (size_t)b * PP + seg0))[lane];
    const int    pid0 = seg0 + 2 * lane;
    const float  nx0  = nf0 * (float)(pid0 >> 9);
    const float  nx1a = nf1 * (float)(pid0 & (WW - 1));

    // block-uniform bases for scalar (SGPR) loads in A
    const float* __restrict__ gtb = gt     + (size_t)b * GG * 2;
    const float* __restrict__ pyb = prob_y + (size_t)b * GG;

    // ===== A: term-1 for own 2 pixels; gt data via s_load (uniform addr) =====
    float ma = BIGF, mb = BIGF;
#pragma unroll
    for (int g = 0; g < GG; ++g) {
        float sgx = gtb[2 * g];          // uniform -> SGPR
        float sgy = gtb[2 * g + 1];      // uniform -> SGPR
        float spy = pyb[g];              // uniform -> SGPR
        float dx  = fmaf(-nf0, sgx, nx0);
        float dx2 = dx * dx;
        float da  = fmaf(-nf1, sgy, nx1a);
        float db  = da + nf1;
        float pq  = spy * spy;
        ma = fminf(ma, pq * fmaf(da, da, dx2));   // min_g (py^2 * d^2)
        mb = fminf(mb, pq * fmaf(db, db, dx2));
    }
    float t1 = p2.x * __builtin_amdgcn_sqrtf(ma) + p2.y * __builtin_amdgcn_sqrtf(mb);
    float ne = p2.x + p2.y;

    // ===== B: term-2; lane owns g; p broadcast via readlane; incremental dy =====
    // dense = (1-p)M + p*py*d = M + p*(py*d - M);  dx^2 loop-invariant per segment
    const float dxw  = nf0 * (float)(seg0 >> 9) - gx;
    const float dx2w = dxw * dxw;
    const float negM = -MAX_DIST;
    const float posM =  MAX_DIST;
    float dya  = nf1 * (float)(seg0 & (WW - 1)) - gy;   // dy of pixel 0
    float dyb  = dya + nf1;                             // dy of pixel 1
    const float step = nf1 + nf1;
    float gm0 = BIGF, gm1 = BIGF;
#pragma unroll
    for (int k = 0; k < 64; ++k) {
        float qa  = rdlane(p2.x, k);              // p of pixel seg0+2k   (SGPR)
        float qb  = rdlane(p2.y, k);              // p of pixel seg0+2k+1 (SGPR)
        float ea  = __builtin_amdgcn_sqrtf(fmaf(dya, dya, dx2w));
        float eb  = __builtin_amdgcn_sqrtf(fmaf(dyb, dyb, dx2w));
        gm0 = fminf(gm0, fmaf(qa, fmaf(py, ea, negM), posM));
        gm1 = fminf(gm1, fmaf(qb, fmaf(py, eb, negM), posM));
        dya += step;
        dyb += step;
    }
    wmin[wave][lane] = fminf(gm0, gm1);

    // ===== block reductions =====
#pragma unroll
    for (int off = 1; off < 64; off <<= 1) {
        t1 += __shfl_xor(t1, off);
        ne += __shfl_xor(ne, off);
    }
    if (lane == 0) { s_t1[wave] = t1; s_ne[wave] = ne; }
    __syncthreads();

    if (tid == 0) {
        float st = 0.0f, sn = 0.0f;
#pragma unroll
        for (int w = 0; w < 8; ++w) { st += s_t1[w]; sn += s_ne[w]; }
        ws[256  + b * NT + t] = st;
        ws[1280 + b * NT + t] = sn;
    }
    if (tid < GG) {
        float v = wmin[0][tid];
#pragma unroll
        for (int w = 1; w < 8; ++w) v = fminf(v, wmin[w][tid]);
        // device-scope atomicMin on uint bits: order-preserving for floats >= 0
        atomicMin(reinterpret_cast<unsigned*>(ws) + b * GG + tid, __float_as_uint(v));
    }
}

__global__ void ghd_final(const float* __restrict__ prob_y,
                          const float* __restrict__ ws,
                          float*       __restrict__ out) {
    // 256 threads: wave b handles batch b, lane = g
    const int tid = threadIdx.x;
    const int b = tid >> 6;
    const int g = tid & 63;

    float mv  = __uint_as_float(reinterpret_cast<const unsigned*>(ws)[b * GG + g]);
    float py  = prob_y[b * GG + g];
    float pyf = (py > 0.2f) ? py : 0.0f;

    // t1 / ne partial sums: lane loads float4 (64 lanes x 4 = 256 tiles)
    float4 tv = ((const float4*)(ws + 256))[b * (NT / 4) + g];
    float4 nv = ((const float4*)(ws + 1280))[b * (NT / 4) + g];
    float t1s = tv.x + tv.y + tv.z + tv.w;
    float nes = nv.x + nv.y + nv.z + nv.w;

#pragma unroll
    for (int off = 1; off < 64; off <<= 1) {
        mv  += __shfl_xor(mv, off);
        pyf += __shfl_xor(pyf, off);
        t1s += __shfl_xor(t1s, off);
        nes += __shfl_xor(nes, off);
    }
    __shared__ float res[4];
    if (g == 0) res[b] = t1s / (nes + EPSV) + mv / (pyf + EPSV);
    __syncthreads();
    if (tid == 0) out[0] = 0.25f * (res[0] + res[1] + res[2] + res[3]);
}

extern "C" void kernel_launch(void* const* d_in, const int* in_sizes, int n_in,
                              void* d_out, int out_size, void* d_ws, size_t ws_size,
                              hipStream_t stream) {
    const float* prob_map = (const float*)d_in[0];
    const float* prob_y   = (const float*)d_in[1];
    const float* gt       = (const float*)d_in[2];
    const int*   osz      = (const int*)d_in[3];
    float* out = (float*)d_out;
    float* ws  = (float*)d_ws;

    // init gmin bits to 0x7f7f7f7f (3.39e38) — larger than any dense value (<= ~1448)
    hipMemsetAsync(ws, 0x7f, BB * GG * sizeof(unsigned), stream);

    dim3 grid(NT, BB);   // 1024 blocks = exactly 4 blocks/CU on 256 CUs
    ghd_main<<<grid, THREADS, 0, stream>>>(prob_map, prob_y, gt, osz, ws);
    ghd_final<<<1, 256, 0, stream>>>(prob_y, ws, out);
}

// Round 19
// 82.938 us; speedup vs baseline: 2.3634x; 1.0114x over previous
//
#include <hip/hip_runtime.h>
#include <math.h>

#define HH 512
#define WW 512
#define PP (HH * WW)          // 262144 pixels
#define GG 64                 // gt points per batch
#define BB 4                  // batches
#define THREADS 512
#define TILE 1024             // pixels per block (8 waves x 128-px segments)
#define NT (PP / TILE)        // 256 tiles per batch -> grid 256x4 = 1024 = exactly 4 blocks/CU
#define MAX_DIST 724.0773439350246f   // sqrt(512^2 + 512^2)
#define EPSV 1e-6f
#define BIGF 3.4e38f

// ws layout:
//   gm  uint bits [BB][GG] : ws[0    .. 255]    (init 0x7f7f7f7f via memset)
//   t1p [BB][NT]           : ws[256  .. 1279]   (write-only partials, no init)
//   nep [BB][NT]           : ws[1280 .. 2303]

__device__ __forceinline__ float rdlane(float v, int l) {
    return __int_as_float(__builtin_amdgcn_readlane(__float_as_int(v), l));
}

__launch_bounds__(THREADS, 8)
__global__ void ghd_main(const float* __restrict__ prob_map,
                         const float* __restrict__ prob_y,
                         const float* __restrict__ gt,
                         const int*   __restrict__ osz,
                         float*       __restrict__ ws) {
    const int t    = blockIdx.x;   // tile
    const int b    = blockIdx.y;   // batch
    const int tid  = threadIdx.x;
    const int lane = tid & 63;
    const int wave = tid >> 6;     // 8 waves

    __shared__ float wmin[8][GG];
    __shared__ float s_t1[8], s_ne[8];

    const float nf0 = (float)osz[2 * b]     * (1.0f / HH);
    const float nf1 = (float)osz[2 * b + 1] * (1.0f / WW);

    // lane l owns gt point l — normalized coords + weights in registers
    const float2 gxy = ((const float2*)gt)[b * GG + lane];
    const float  gx  = nf0 * gxy.x;       // row coord
    const float  gy  = nf1 * gxy.y;       // col coord
    const float  py  = prob_y[b * GG + lane];
    const float  pyq = py * py;

    // own 2 adjacent pixels; wave's 128-px segment lies within ONE image row
    const int    seg0 = t * TILE + wave * 128;
    const float2 p2   = ((const float2*)(prob_map + (size_t)b * PP + seg0))[lane];
    const int    pid0 = seg0 + 2 * lane;
    const float  nx0  = nf0 * (float)(pid0 >> 9);          // row (wave-uniform value)
    const float  nx1a = nf1 * (float)(pid0 & (WW - 1));    // col of own pixel 0

    // per-lane-g row distance (shared by A-bound and B)
    const float dxw  = nf0 * (float)(seg0 >> 9) - gx;
    const float dx2w = dxw * dxw;

    // ===== A-prune: exact candidate mask for this 128-px row strip ==========
    // strip columns span [c0, c0 + 127*nf1]
    const float c0  = nf1 * (float)(seg0 & (WW - 1));
    const float cL  = c0 - gy;                 // dy at left end
    const float cR  = (c0 + 127.0f * nf1) - gy;// dy at right end
    const float dmn = fmaxf(fmaxf(cL, -cR), 0.0f);   // min |dy| over strip
    const float dmx = fmaxf(cR, -cL);                // max |dy| over strip
    const float vmin = pyq * fmaf(dmn, dmn, dx2w);
    const float vmax = pyq * fmaf(dmx, dmx, dx2w);
    float thr = vmax;
#pragma unroll
    for (int off = 1; off < 64; off <<= 1)
        thr = fminf(thr, __shfl_xor(thr, off));
    const unsigned long long cand = __ballot(vmin <= thr);   // wave-uniform mask

    // ===== A: term-1 for own 2 pixels over candidate g only (readlane) ======
    float ma = BIGF, mb = BIGF;
    unsigned long long m = cand;
    while (m) {
        const int g = (int)__ffsll(m) - 1;     // wave-uniform scalar loop
        m &= m - 1;
        float sgx = rdlane(gx,  g);
        float sgy = rdlane(gy,  g);
        float spq = rdlane(pyq, g);
        float dx  = nx0 - sgx;
        float dx2 = dx * dx;
        float da  = nx1a - sgy;
        float db  = da + nf1;
        ma = fminf(ma, spq * fmaf(da, da, dx2));   // min_g (py^2 * d^2)
        mb = fminf(mb, spq * fmaf(db, db, dx2));
    }
    float t1 = p2.x * __builtin_amdgcn_sqrtf(ma) + p2.y * __builtin_amdgcn_sqrtf(mb);
    float ne = p2.x + p2.y;

    // ===== B: term-2; lane owns g; p broadcast via readlane; incremental dy =====
    // dense = (1-p)M + p*py*d = M + p*(py*d - M);  dx^2 loop-invariant per segment
    const float negM = -MAX_DIST;
    const float posM =  MAX_DIST;
    float dya  = c0 - gy;                      // dy of pixel 0
    float dyb  = dya + nf1;                    // dy of pixel 1
    const float step = nf1 + nf1;
    float gm0 = BIGF, gm1 = BIGF;
#pragma unroll
    for (int k = 0; k < 64; ++k) {
        float qa  = rdlane(p2.x, k);              // p of pixel seg0+2k   (SGPR)
        float qb  = rdlane(p2.y, k);              // p of pixel seg0+2k+1 (SGPR)
        float ea  = __builtin_amdgcn_sqrtf(fmaf(dya, dya, dx2w));
        float eb  = __builtin_amdgcn_sqrtf(fmaf(dyb, dyb, dx2w));
        gm0 = fminf(gm0, fmaf(qa, fmaf(py, ea, negM), posM));
        gm1 = fminf(gm1, fmaf(qb, fmaf(py, eb, negM), posM));
        dya += step;
        dyb += step;
    }
    wmin[wave][lane] = fminf(gm0, gm1);

    // ===== block reductions =====
#pragma unroll
    for (int off = 1; off < 64; off <<= 1) {
        t1 += __shfl_xor(t1, off);
        ne += __shfl_xor(ne, off);
    }
    if (lane == 0) { s_t1[wave] = t1; s_ne[wave] = ne; }
    __syncthreads();

    if (tid == 0) {
        float st = 0.0f, sn = 0.0f;
#pragma unroll
        for (int w = 0; w < 8; ++w) { st += s_t1[w]; sn += s_ne[w]; }
        ws[256  + b * NT + t] = st;
        ws[1280 + b * NT + t] = sn;
    }
    if (tid < GG) {
        float v = wmin[0][tid];
#pragma unroll
        for (int w = 1; w < 8; ++w) v = fminf(v, wmin[w][tid]);
        // device-scope atomicMin on uint bits: order-preserving for floats >= 0
        atomicMin(reinterpret_cast<unsigned*>(ws) + b * GG + tid, __float_as_uint(v));
    }
}

__global__ void ghd_final(const float* __restrict__ prob_y,
                          const float* __restrict__ ws,
                          float*       __restrict__ out) {
    // 256 threads: wave b handles batch b, lane = g
    const int tid = threadIdx.x;
    const int b = tid >> 6;
    const int g = tid & 63;

    float mv  = __uint_as_float(reinterpret_cast<const unsigned*>(ws)[b * GG + g]);
    float py  = prob_y[b * GG + g];
    float pyf = (py > 0.2f) ? py : 0.0f;

    // t1 / ne partial sums: lane loads float4 (64 lanes x 4 = 256 tiles)
    float4 tv = ((const float4*)(ws + 256))[b * (NT / 4) + g];
    float4 nv = ((const float4*)(ws + 1280))[b * (NT / 4) + g];
    float t1s = tv.x + tv.y + tv.z + tv.w;
    float nes = nv.x + nv.y + nv.z + nv.w;

#pragma unroll
    for (int off = 1; off < 64; off <<= 1) {
        mv  += __shfl_xor(mv, off);
        pyf += __shfl_xor(pyf, off);
        t1s += __shfl_xor(t1s, off);
        nes += __shfl_xor(nes, off);
    }
    __shared__ float res[4];
    if (g == 0) res[b] = t1s / (nes + EPSV) + mv / (pyf + EPSV);
    __syncthreads();
    if (tid == 0) out[0] = 0.25f * (res[0] + res[1] + res[2] + res[3]);
}

extern "C" void kernel_launch(void* const* d_in, const int* in_sizes, int n_in,
                              void* d_out, int out_size, void* d_ws, size_t ws_size,
                              hipStream_t stream) {
    const float* prob_map = (const float*)d_in[0];
    const float* prob_y   = (const float*)d_in[1];
    const float* gt       = (const float*)d_in[2];
    const int*   osz      = (const int*)d_in[3];
    float* out = (float*)d_out;
    float* ws  = (float*)d_ws;

    // init gmin bits to 0x7f7f7f7f (3.39e38) — larger than any dense value (<= ~1448)
    hipMemsetAsync(ws, 0x7f, BB * GG * sizeof(unsigned), stream);

    dim3 grid(NT, BB);   // 1024 blocks = exactly 4 blocks/CU on 256 CUs
    ghd_main<<<grid, THREADS, 0, stream>>>(prob_map, prob_y, gt, osz, ws);
    ghd_final<<<1, 256, 0, stream>>>(prob_y, ws, out);
}